// Round 4
// baseline (39.908 us; speedup 1.0000x reference)
//
#include <hip/hip_runtime.h>
#include <math.h>

#define BB 64
#define LL 512
#define DD 768
#define HH 768
#define KK 128

static __device__ __forceinline__ float4 fmax4(float4 a, float4 b) {
    float4 r;
    r.x = fmaxf(a.x, b.x); r.y = fmaxf(a.y, b.y);
    r.z = fmaxf(a.z, b.z); r.w = fmaxf(a.w, b.w);
    return r;
}

// ---------------------------------------------------------------------------
// K1: fused {ballot-scan compaction + span-max gather + GEMM1(relu)}
// grid: (12 j-tiles of 64, 8 b-tiles of 8) = 96 blocks ; block: 512 (8 waves).
// wave w owns batch bbase+w end-to-end for scan+gather; GEMM1 reuses the
// 8-batch feat panel in LDS exactly as R3-B.
// ---------------------------------------------------------------------------
__global__ __launch_bounds__(512) void halton_featmlp1_kernel(
    const float* __restrict__ enc,        // (B, L, D)
    const float* __restrict__ W1,         // (D, H)
    const float* __restrict__ b1,         // (H)
    const int*   __restrict__ valid_mask, // (B, L)
    const int*   __restrict__ pos_span,   // (B, 2)
    float*       __restrict__ h)          // (B, H)
{
    __shared__ int   s_idx[8][40];
    __shared__ int   s_count[8];
    __shared__ float s_feat[8][DD];       // 24 KB

    const int tid   = threadIdx.x;
    const int jbase = blockIdx.x * 64;
    const int bbase = blockIdx.y * 8;
    const int w     = tid >> 6;           // wave 0..7
    const int lane  = tid & 63;
    const int b     = bbase + w;

    // ---- Phase 0: per-wave ballot scan of valid_mask row -> compacted idx
    {
        int count = 0;
        #pragma unroll
        for (int c = 0; c < LL / 64; ++c) {
            int l = c * 64 + lane;
            int v = valid_mask[b * LL + l];
            unsigned long long mk = __ballot(v == 1);
            if (v == 1) {
                int rank = count + __popcll(mk & ((1ull << lane) - 1ull));
                if (rank < 40) s_idx[w][rank] = l;
            }
            count += __popcll(mk);
        }
        if (lane == 0) s_count[w] = count;
    }
    __syncthreads();

    // ---- Phase 1: span-max gather, wave w -> s_feat[w][:]
    {
        const int lo    = pos_span[b * 2 + 0];
        const int hi    = pos_span[b * 2 + 1];   // <= 39
        const int count = s_count[w];
        const int pend  = min(hi, count - 1);

        float4 m0 = make_float4(-INFINITY, -INFINITY, -INFINITY, -INFINITY);
        float4 m1 = m0, m2 = m0;
        for (int p = lo; p <= pend; ++p) {
            const float4* r4 = (const float4*)&enc[((long)b * LL + s_idx[w][p]) * DD];
            m0 = fmax4(m0, r4[0 * 64 + lane]);   // 3 independent 1KB wave-loads
            m1 = fmax4(m1, r4[1 * 64 + lane]);
            m2 = fmax4(m2, r4[2 * 64 + lane]);
        }
        if (hi >= count) {                       // zero row(s) inside span
            float4 z = make_float4(0.f, 0.f, 0.f, 0.f);
            m0 = fmax4(m0, z); m1 = fmax4(m1, z); m2 = fmax4(m2, z);
        }
        float4* f4 = (float4*)&s_feat[w][0];
        f4[0 * 64 + lane] = m0;
        f4[1 * 64 + lane] = m1;
        f4[2 * 64 + lane] = m2;
    }
    __syncthreads();

    // ---- Phase 2: h[b, j] = relu(feat[b,:] . W1[:,j] + b1[j])
    {
        const int j = jbase + lane;
        const float4* f4 = (const float4*)&s_feat[w][0];
        const float*  wp = &W1[j];

        float acc0 = b1[j], acc1 = 0.0f, acc2 = 0.0f, acc3 = 0.0f;
        #pragma unroll 4
        for (int k4 = 0; k4 < DD / 4; ++k4) {
            const float4 fv = f4[k4];            // LDS b128 broadcast
            const float* wk = &wp[k4 * 4 * HH];
            acc0 += fv.x * wk[0 * HH];           // coalesced, L1-shared across waves
            acc1 += fv.y * wk[1 * HH];
            acc2 += fv.z * wk[2 * HH];
            acc3 += fv.w * wk[3 * HH];
        }
        h[(long)b * HH + j] = fmaxf((acc0 + acc1) + (acc2 + acc3), 0.0f);
    }
}

// ---------------------------------------------------------------------------
// K2: logits = h @ W2 + b2
// grid: 64 blocks (one per batch) ; block: 256 (4 waves).
// thread: col = tid&127, khalf = tid>>7 -> each sums 384 k's; LDS combine.
// ---------------------------------------------------------------------------
__global__ __launch_bounds__(256) void halton_gemm2_kernel(
    const float* __restrict__ h,     // (B, H)
    const float* __restrict__ W2,    // (H, K)
    const float* __restrict__ b2,    // (K)
    float*       __restrict__ out)   // (B, K)
{
    __shared__ float s_h[HH];        // 3 KB
    __shared__ float s_part[KK];

    const int b   = blockIdx.x;
    const int tid = threadIdx.x;

    if (tid < HH / 4) ((float4*)s_h)[tid] = ((const float4*)&h[(long)b * HH])[tid];
    __syncthreads();

    const int col = tid & 127;
    const int kh  = tid >> 7;        // 0..1, uniform per wave
    const float4* h4 = (const float4*)&s_h[kh * (HH / 2)];
    const float*  wp = &W2[kh * (HH / 2) * KK + col];

    float a0 = 0.f, a1 = 0.f, a2 = 0.f, a3 = 0.f;
    #pragma unroll 8
    for (int j4 = 0; j4 < HH / 8; ++j4) {
        const float4 hv = h4[j4];    // LDS b128 broadcast
        const float* wj = &wp[j4 * 4 * KK];
        a0 += hv.x * wj[0 * KK];     // coalesced
        a1 += hv.y * wj[1 * KK];
        a2 += hv.z * wj[2 * KK];
        a3 += hv.w * wj[3 * KK];
    }
    const float part = (a0 + a1) + (a2 + a3);
    if (kh == 1) s_part[col] = part;
    __syncthreads();
    if (kh == 0) out[b * KK + col] = part + s_part[col] + b2[col];
}

extern "C" void kernel_launch(void* const* d_in, const int* in_sizes, int n_in,
                              void* d_out, int out_size, void* d_ws, size_t ws_size,
                              hipStream_t stream) {
    const float* enc        = (const float*)d_in[0];
    const float* W1         = (const float*)d_in[1];
    const float* b1         = (const float*)d_in[2];
    const float* W2         = (const float*)d_in[3];
    const float* b2         = (const float*)d_in[4];
    const int*   valid_mask = (const int*)d_in[5];
    const int*   pos_span   = (const int*)d_in[6];
    // d_in[7] = mask_span: dead code (mask_feat unused by the reference output)
    float* out = (float*)d_out;
    float* h   = (float*)d_ws;       // 64*768 floats

    halton_featmlp1_kernel<<<dim3(12, 8), 512, 0, stream>>>(enc, W1, b1,
                                                            valid_mask, pos_span, h);
    halton_gemm2_kernel<<<BB, 256, 0, stream>>>(h, W2, b2, out);
}

// Round 5
// 30.683 us; speedup vs baseline: 1.3006x; 1.3006x over previous
//
#include <hip/hip_runtime.h>
#include <math.h>

#define BB 64
#define LL 512
#define DD 768
#define HH 768
#define KK 128

static __device__ __forceinline__ float4 fmax4(float4 a, float4 b) {
    float4 r;
    r.x = fmaxf(a.x, b.x); r.y = fmaxf(a.y, b.y);
    r.z = fmaxf(a.z, b.z); r.w = fmaxf(a.w, b.w);
    return r;
}

// ws layout (floats): feat[64*768] | h[64*768]
#define FEAT_OFF 0
#define H_OFF    (BB * DD)

// ---------------------------------------------------------------------------
// Kernel A: compaction scan + span-max gather, latency-optimized.
// grid: (B, 3 parts) = 192 blocks ; block: 512 (8 waves).
// thread: c4 = tid&63 (float4 column within part), g = tid>>6 (row-group 0..7).
// Each thread covers ceil(n/8) <= 5 span rows; LDS fmax tree combines groups.
// ---------------------------------------------------------------------------
__global__ __launch_bounds__(512) void halton_feat_kernel(
    const float* __restrict__ enc,        // (B, L, D)
    const int*   __restrict__ valid_mask, // (B, L)
    const int*   __restrict__ pos_span,   // (B, 2)
    float*       __restrict__ feat)       // (B, D)
{
    __shared__ int    s_idx[40];
    __shared__ int    s_count;
    __shared__ float4 s_red[8][64];       // 8 KB

    const int b    = blockIdx.x;
    const int part = blockIdx.y;          // 0..2
    const int tid  = threadIdx.x;

    // wave 0: ballot scan of valid_mask row -> compacted indices
    if (tid < 64) {
        int count = 0;
        #pragma unroll
        for (int c = 0; c < LL / 64; ++c) {
            int l = c * 64 + tid;
            int v = valid_mask[b * LL + l];
            unsigned long long mk = __ballot(v == 1);
            if (v == 1) {
                int rank = count + __popcll(mk & ((1ull << tid) - 1ull));
                if (rank < 40) s_idx[rank] = l;
            }
            count += __popcll(mk);
        }
        if (tid == 0) s_count = count;
    }
    __syncthreads();

    const int count = s_count;
    const int lo    = pos_span[b * 2 + 0];
    const int hi    = pos_span[b * 2 + 1];   // <= 39 by construction
    const int pend  = min(hi, count - 1);

    const int c4 = tid & 63;              // float4 column within this part
    const int g  = tid >> 6;              // row-group 0..7
    const int fcol = part * 64 + c4;      // float4 index within the 192-wide row

    float4 m = make_float4(-INFINITY, -INFINITY, -INFINITY, -INFINITY);
    for (int p = lo + g; p <= pend; p += 8) {
        m = fmax4(m, ((const float4*)&enc[((long)b * LL + s_idx[p]) * DD])[fcol]);
    }
    if (hi >= count) {                    // zero row(s) inside span
        m = fmax4(m, make_float4(0.f, 0.f, 0.f, 0.f));
    }
    s_red[g][c4] = m;
    __syncthreads();

    if (g == 0) {
        float4 r = s_red[0][c4];
        #pragma unroll
        for (int q = 1; q < 8; ++q) r = fmax4(r, s_red[q][c4]);
        ((float4*)&feat[(long)b * DD])[fcol] = r;
    }
}

// ---------------------------------------------------------------------------
// Kernel B: h = relu(feat @ W1 + b1)
// grid: (12 j-tiles of 64, 8 b-tiles of 8) = 96 blocks ; block: 512 (8 waves).
// thread: j = tid&63 (column), bl = tid>>6 (batch). float4 LDS broadcast,
// 4 accumulators break the FMA chain.
// ---------------------------------------------------------------------------
__global__ __launch_bounds__(512) void halton_gemm1_kernel(
    const float* __restrict__ feat,  // (B, D)
    const float* __restrict__ W1,    // (D, H)
    const float* __restrict__ b1,    // (H)
    float*       __restrict__ h)     // (B, H)
{
    __shared__ float s_feat[8 * DD]; // 24 KB

    const int tid   = threadIdx.x;
    const int jbase = blockIdx.x * 64;
    const int bbase = blockIdx.y * 8;

    {
        const float4* src = (const float4*)&feat[bbase * DD];
        float4*       dst = (float4*)s_feat;
        for (int i = tid; i < 8 * DD / 4; i += 512) dst[i] = src[i];
    }
    __syncthreads();

    const int j  = jbase + (tid & 63);
    const int bl = tid >> 6;              // 0..7, uniform per wave
    const float4* f4 = (const float4*)&s_feat[bl * DD];
    const float*  wp = &W1[j];

    float acc0 = b1[j], acc1 = 0.0f, acc2 = 0.0f, acc3 = 0.0f;
    #pragma unroll 4
    for (int k4 = 0; k4 < DD / 4; ++k4) {
        const float4 fv = f4[k4];         // LDS b128 broadcast (wave-uniform)
        const float* wk = &wp[k4 * 4 * HH];
        acc0 += fv.x * wk[0 * HH];        // coalesced, L1-shared across waves
        acc1 += fv.y * wk[1 * HH];
        acc2 += fv.z * wk[2 * HH];
        acc3 += fv.w * wk[3 * HH];
    }
    h[(long)(bbase + bl) * HH + j] = fmaxf((acc0 + acc1) + (acc2 + acc3), 0.0f);
}

// ---------------------------------------------------------------------------
// Kernel C: logits = h @ W2 + b2
// grid: 64 blocks (one per batch) ; block: 256 (4 waves).
// thread: col = tid&127, kh = tid>>7 -> each sums 384 k's; LDS combine.
// ---------------------------------------------------------------------------
__global__ __launch_bounds__(256) void halton_gemm2_kernel(
    const float* __restrict__ h,     // (B, H)
    const float* __restrict__ W2,    // (H, K)
    const float* __restrict__ b2,    // (K)
    float*       __restrict__ out)   // (B, K)
{
    __shared__ float s_h[HH];        // 3 KB
    __shared__ float s_part[KK];

    const int b   = blockIdx.x;
    const int tid = threadIdx.x;

    if (tid < HH / 4) ((float4*)s_h)[tid] = ((const float4*)&h[(long)b * HH])[tid];
    __syncthreads();

    const int col = tid & 127;
    const int kh  = tid >> 7;        // 0..1, uniform per wave
    const float4* h4 = (const float4*)&s_h[kh * (HH / 2)];
    const float*  wp = &W2[kh * (HH / 2) * KK + col];

    float a0 = 0.f, a1 = 0.f, a2 = 0.f, a3 = 0.f;
    #pragma unroll 8
    for (int j4 = 0; j4 < HH / 8; ++j4) {
        const float4 hv = h4[j4];    // LDS b128 broadcast
        const float* wj = &wp[j4 * 4 * KK];
        a0 += hv.x * wj[0 * KK];     // coalesced
        a1 += hv.y * wj[1 * KK];
        a2 += hv.z * wj[2 * KK];
        a3 += hv.w * wj[3 * KK];
    }
    const float part = (a0 + a1) + (a2 + a3);
    if (kh == 1) s_part[col] = part;
    __syncthreads();
    if (kh == 0) out[b * KK + col] = part + s_part[col] + b2[col];
}

extern "C" void kernel_launch(void* const* d_in, const int* in_sizes, int n_in,
                              void* d_out, int out_size, void* d_ws, size_t ws_size,
                              hipStream_t stream) {
    const float* enc        = (const float*)d_in[0];
    const float* W1         = (const float*)d_in[1];
    const float* b1         = (const float*)d_in[2];
    const float* W2         = (const float*)d_in[3];
    const float* b2         = (const float*)d_in[4];
    const int*   valid_mask = (const int*)d_in[5];
    const int*   pos_span   = (const int*)d_in[6];
    // d_in[7] = mask_span: dead code (mask_feat unused by the reference output)
    float* out  = (float*)d_out;
    float* feat = (float*)d_ws + FEAT_OFF;
    float* h    = (float*)d_ws + H_OFF;

    halton_feat_kernel<<<dim3(BB, 3), 512, 0, stream>>>(enc, valid_mask, pos_span, feat);
    halton_gemm1_kernel<<<dim3(12, 8), 512, 0, stream>>>(feat, W1, b1, h);
    halton_gemm2_kernel<<<BB, 256, 0, stream>>>(h, W2, b2, out);
}